// Round 6
// baseline (5476.183 us; speedup 1.0000x reference)
//
#include <hip/hip_runtime.h>
#include <hip/hip_bf16.h>

typedef short bf16x8 __attribute__((ext_vector_type(8)));
typedef float f32x4 __attribute__((ext_vector_type(4)));
using bf16 = __hip_bfloat16;

// ---------------------------------------------------------------- utilities
// gelu(x) = 0.5x(1+tanh(0.79788456x(1+0.044715x^2))) = x * sigmoid(1.5957691x(1+0.044715x^2))
static __device__ __forceinline__ float gelu_f(float x) {
    float u = 1.5957691216057308f * x * (1.0f + 0.044715f * x * x);
    return x / (1.0f + __expf(-u));
}

static __device__ __forceinline__ unsigned pack_bf16(float lo, float hi) {
    union { bf16 h; unsigned short u; } a, b;
    a.h = __float2bfloat16(lo);
    b.h = __float2bfloat16(hi);
    return ((unsigned)b.u << 16) | (unsigned)a.u;
}

// ---------------------------------------------------------------- transpose + downcast (f32 -> bf16), batched over z
__global__ __launch_bounds__(256) void transpose_f32_bf16(const float* __restrict__ in,
                                                          bf16* __restrict__ out,
                                                          int R, int C, size_t zso) {
    __shared__ float tile[32][33];
    size_t zi = (size_t)blockIdx.z * R * C;
    size_t zo = (size_t)blockIdx.z * zso;
    int c0 = blockIdx.x * 32, r0 = blockIdx.y * 32;
    int tx = threadIdx.x & 31, ty = threadIdx.x >> 5;
    #pragma unroll
    for (int i = 0; i < 32; i += 8) {
        int r = r0 + ty + i, c = c0 + tx;
        if (r < R && c < C) tile[ty + i][tx] = in[zi + (size_t)r * C + c];
    }
    __syncthreads();
    #pragma unroll
    for (int i = 0; i < 32; i += 8) {
        int c = c0 + ty + i, r = r0 + tx;
        if (c < C && r < R) out[zo + (size_t)c * R + r] = __float2bfloat16(tile[tx][ty + i]);
    }
}

// ---------------------------------------------------------------- bias concat: [L][1536] = bq|bk|bv
__global__ __launch_bounds__(256) void concat_bias(const float* __restrict__ bq,
                                                   const float* __restrict__ bk,
                                                   const float* __restrict__ bv,
                                                   float* __restrict__ out) {
    int i = blockIdx.x * 256 + threadIdx.x;
    if (i < 3 * 1536) {
        int L = i / 1536, r = i - L * 1536;
        float v = (r < 512) ? bq[L * 512 + r]
                : (r < 1024) ? bk[L * 512 + r - 512]
                             : bv[L * 512 + r - 1024];
        out[i] = v;
    }
}

// ---------------------------------------------------------------- V transpose: qkv[b*240+t][1536] (cols 1024..1535) -> vt[b*512+d][240]
__global__ __launch_bounds__(256) void transpose_v(const bf16* __restrict__ in,
                                                   bf16* __restrict__ out) {
    __shared__ bf16 tile[32][33];
    int b = blockIdx.z;
    int d0 = blockIdx.x * 32, t0 = blockIdx.y * 32;
    int tx = threadIdx.x & 31, ty = threadIdx.x >> 5;
    #pragma unroll
    for (int i = 0; i < 32; i += 8) {
        int tt = t0 + ty + i, dd = d0 + tx;
        if (tt < 240) tile[ty + i][tx] = in[((size_t)b * 240 + tt) * 1536 + 1024 + dd];
    }
    __syncthreads();
    #pragma unroll
    for (int i = 0; i < 32; i += 8) {
        int dd = d0 + ty + i, tt = t0 + tx;
        if (tt < 240) out[((size_t)b * 512 + dd) * 240 + tt] = tile[tx][ty + i];
    }
}

// ---------------------------------------------------------------- patch embedding + positional encoding
__global__ __launch_bounds__(256) void embed_kernel(const float* __restrict__ x_enc,
                                                    const float* __restrict__ W_emb, // [16][512]
                                                    bf16* __restrict__ h) {
    int row = blockIdx.x;
    int b = row / 240, l = row - b * 240;
    int s = (l < 16) ? 0 : (l < 48) ? 1 : (l < 112) ? 2 : 3;
    int len = 16 << s;
    int off = len - 16;           // 0,16,48,112
    int kk = 8 >> s;              // 8,4,2,1
    int j = l - off;
    int bs_i = b >> 5, c_i = b & 31;
    __shared__ float xv[16];
    int t = threadIdx.x;
    if (t < 16) {
        int tau = (j * 16 + t) * kk;
        xv[t] = x_enc[((size_t)bs_i * 2048 + tau) * 32 + c_i];
    }
    __syncthreads();
    int pe_row = j * kk;
    const float NEG2LN = -0.035977892078032f; // -2*ln(10000)/512
    for (int d = t; d < 512; d += 256) {
        float acc = 0.f;
        #pragma unroll
        for (int i = 0; i < 16; ++i) acc += xv[i] * W_emb[i * 512 + d];
        int di = d >> 1;
        float ang = (float)pe_row * expf((float)di * NEG2LN);
        float pos = (d & 1) ? cosf(ang) : sinf(ang);
        h[(size_t)row * 512 + d] = __float2bfloat16(acc + pos);
    }
}

// ---------------------------------------------------------------- no-LDS GEMM: C[M,N] = A[M,K] @ Bt[N,K]^T + bias (+gelu)
// Each wave owns an independent 64x128 tile (4x8 grid of 16x16x32 MFMA).
// A/B fragments are loaded DIRECTLY from global (L1/L2) into registers:
// frag = 16 B/lane at row (base + l16), k-chunk quad*8 — no LDS, no barriers.
// K is a template param so the 16-chunk inner loop fully unrolls and all
// load offsets fold into immediate offsets on 12 persistent base pointers.
template<int K>
__global__ __launch_bounds__(256) void gemm_direct(const bf16* __restrict__ A,
                                                   const bf16* __restrict__ Bt,
                                                   const float* __restrict__ bias,
                                                   bf16* __restrict__ C,
                                                   int N, int act) {
    const int t = threadIdx.x;
    const int wave = t >> 6, lane = t & 63;
    const int quad = lane >> 4, l16 = lane & 15;
    const int m0 = blockIdx.y * 128 + (wave >> 1) * 64;
    const int n0 = blockIdx.x * 256 + (wave & 1) * 128;

    f32x4 acc[4][8];
    #pragma unroll
    for (int mi = 0; mi < 4; ++mi)
        #pragma unroll
        for (int ni = 0; ni < 8; ++ni)
            #pragma unroll
            for (int r = 0; r < 4; ++r) acc[mi][ni][r] = 0.0f;

    const bf16* Ab = A + (size_t)(m0 + l16) * K + quad * 8;
    const bf16* Bb = Bt + (size_t)(n0 + l16) * K + quad * 8;

    for (int ko = 0; ko < K; ko += 512) {
        #pragma unroll
        for (int kc = 0; kc < 512; kc += 32) {
            bf16x8 af[4], bfr[8];
            #pragma unroll
            for (int mi = 0; mi < 4; ++mi)
                af[mi] = *(const bf16x8*)(Ab + (size_t)mi * 16 * K + ko + kc);
            #pragma unroll
            for (int ni = 0; ni < 8; ++ni)
                bfr[ni] = *(const bf16x8*)(Bb + (size_t)ni * 16 * K + ko + kc);
            #pragma unroll
            for (int mi = 0; mi < 4; ++mi)
                #pragma unroll
                for (int ni = 0; ni < 8; ++ni)
                    acc[mi][ni] = __builtin_amdgcn_mfma_f32_16x16x32_bf16(af[mi], bfr[ni],
                                                                         acc[mi][ni], 0, 0, 0);
        }
    }

    // epilogue: adjacent l16 lanes hold adjacent cols of the same rows -> pair via shfl_xor(1),
    // store packed bf16x2 dwords
    const int oddl = l16 & 1;
    #pragma unroll
    for (int ni = 0; ni < 8; ++ni) {
        int col = n0 + ni * 16 + l16;
        float bv = bias[col];
        #pragma unroll
        for (int mi = 0; mi < 4; ++mi) {
            float v0 = acc[mi][ni][0] + bv;
            float v1 = acc[mi][ni][1] + bv;
            float v2 = acc[mi][ni][2] + bv;
            float v3 = acc[mi][ni][3] + bv;
            if (act) {
                v0 = gelu_f(v0); v1 = gelu_f(v1);
                v2 = gelu_f(v2); v3 = gelu_f(v3);
            }
            float p0 = __shfl_xor(v0, 1);
            float p1 = __shfl_xor(v1, 1);
            float p2 = __shfl_xor(v2, 1);
            float p3 = __shfl_xor(v3, 1);
            float lo0 = oddl ? p1 : v0, hi0 = oddl ? v1 : p0;
            float lo1 = oddl ? p3 : v2, hi1 = oddl ? v3 : p2;
            int r0 = oddl ? 1 : 0;
            size_t rowb = (size_t)(m0 + mi * 16 + quad * 4);
            unsigned* c0p = (unsigned*)(C + (rowb + r0) * N + (col & ~1));
            unsigned* c1p = (unsigned*)(C + (rowb + r0 + 2) * N + (col & ~1));
            *c0p = pack_bf16(lo0, hi0);
            *c1p = pack_bf16(lo1, hi1);
        }
    }
}

// ---------------------------------------------------------------- MFMA segment attention (qkv fused input, stride 1536)
template<int LEN>
__global__ __launch_bounds__(256) void attn_mfma(const bf16* __restrict__ qkv,
                                                 const bf16* __restrict__ vt,
                                                 bf16* __restrict__ o) {
    constexpr int NT = LEN / 16;
    constexpr int KT = (LEN >= 32) ? (LEN / 32) : 1;
    constexpr int PST = (LEN == 16) ? 40 : (LEN + 8);
    constexpr int SLABS = LEN / 16;
    constexpr int OFF = LEN - 16;
    __shared__ __align__(16) bf16 Plds[4 * 16 * PST];

    const int t = threadIdx.x;
    const int wave = t >> 6, lane = t & 63;
    const int quad = lane >> 4, l16 = lane & 15;
    const int task = blockIdx.x * 4 + wave;
    const int b = task / (8 * SLABS);
    const int rem = task - b * (8 * SLABS);
    const int h = rem / SLABS;
    const int slab = rem - h * SLABS;

    const size_t qbase = ((size_t)b * 240 + OFF) * 1536 + h * 64;
    const size_t obase = ((size_t)b * 240 + OFF) * 512 + h * 64;

    const bf16* qp = qkv + qbase + (size_t)(slab * 16 + l16) * 1536 + quad * 8;
    bf16x8 qf0 = *(const bf16x8*)qp;
    bf16x8 qf1 = *(const bf16x8*)(qp + 32);

    f32x4 sacc[NT];
    #pragma unroll
    for (int nt = 0; nt < NT; ++nt) {
        const bf16* kp = qkv + qbase + 512 + (size_t)(nt * 16 + l16) * 1536 + quad * 8;
        bf16x8 kf0 = *(const bf16x8*)kp;
        bf16x8 kf1 = *(const bf16x8*)(kp + 32);
        f32x4 a = {0.f, 0.f, 0.f, 0.f};
        a = __builtin_amdgcn_mfma_f32_16x16x32_bf16(qf0, kf0, a, 0, 0, 0);
        a = __builtin_amdgcn_mfma_f32_16x16x32_bf16(qf1, kf1, a, 0, 0, 0);
        sacc[nt] = a;
    }

    float mx[4], sm[4];
    #pragma unroll
    for (int r = 0; r < 4; ++r) mx[r] = -3.0e38f;
    #pragma unroll
    for (int nt = 0; nt < NT; ++nt)
        #pragma unroll
        for (int r = 0; r < 4; ++r) {
            sacc[nt][r] *= 0.125f;
            mx[r] = fmaxf(mx[r], sacc[nt][r]);
        }
    #pragma unroll
    for (int msk = 1; msk < 16; msk <<= 1)
        #pragma unroll
        for (int r = 0; r < 4; ++r) mx[r] = fmaxf(mx[r], __shfl_xor(mx[r], msk));
    #pragma unroll
    for (int r = 0; r < 4; ++r) sm[r] = 0.f;
    #pragma unroll
    for (int nt = 0; nt < NT; ++nt)
        #pragma unroll
        for (int r = 0; r < 4; ++r) {
            float p = __expf(sacc[nt][r] - mx[r]);
            sacc[nt][r] = p;
            sm[r] += p;
        }
    #pragma unroll
    for (int msk = 1; msk < 16; msk <<= 1)
        #pragma unroll
        for (int r = 0; r < 4; ++r) sm[r] += __shfl_xor(sm[r], msk);
    float inv[4];
    #pragma unroll
    for (int r = 0; r < 4; ++r) inv[r] = 1.f / sm[r];

    bf16* pw = Plds + wave * 16 * PST;
    #pragma unroll
    for (int nt = 0; nt < NT; ++nt)
        #pragma unroll
        for (int r = 0; r < 4; ++r)
            pw[(quad * 4 + r) * PST + nt * 16 + l16] =
                __float2bfloat16(sacc[nt][r] * inv[r]);
    if (LEN == 16) {
        #pragma unroll
        for (int r = 0; r < 4; ++r)
            pw[(quad * 4 + r) * PST + 16 + l16] = __float2bfloat16(0.f);
    }
    __syncthreads();

    f32x4 oacc[4];
    #pragma unroll
    for (int n4 = 0; n4 < 4; ++n4) {
        f32x4 z = {0.f, 0.f, 0.f, 0.f};
        oacc[n4] = z;
    }
    #pragma unroll
    for (int kt = 0; kt < KT; ++kt) {
        bf16x8 pf = *(const bf16x8*)&pw[l16 * PST + kt * 32 + quad * 8];
        #pragma unroll
        for (int n4 = 0; n4 < 4; ++n4) {
            const bf16* vp = vt + ((size_t)b * 512 + h * 64 + n4 * 16 + l16) * 240
                              + OFF + kt * 32 + quad * 8;
            bf16x8 vf = *(const bf16x8*)vp;
            oacc[n4] = __builtin_amdgcn_mfma_f32_16x16x32_bf16(pf, vf, oacc[n4], 0, 0, 0);
        }
    }
    #pragma unroll
    for (int n4 = 0; n4 < 4; ++n4)
        #pragma unroll
        for (int r = 0; r < 4; ++r)
            o[obase + (size_t)(slab * 16 + quad * 4 + r) * 512 + n4 * 16 + l16] =
                __float2bfloat16(oacc[n4][r]);
}

// ---------------------------------------------------------------- residual + layernorm (row = 512)
__global__ __launch_bounds__(256) void ln_kernel(const bf16* x, const bf16* res,
                                                 const float* __restrict__ g,
                                                 const float* __restrict__ bta,
                                                 bf16* out_bf, float* out_f) {
    int row = blockIdx.x;
    int t = threadIdx.x;
    const bf16* xr = x + (size_t)row * 512;
    float v0 = __bfloat162float(xr[t]);
    float v1 = __bfloat162float(xr[t + 256]);
    if (res) {
        const bf16* rr = res + (size_t)row * 512;
        v0 += __bfloat162float(rr[t]);
        v1 += __bfloat162float(rr[t + 256]);
    }
    float s = v0 + v1, ss = v0 * v0 + v1 * v1;
    #pragma unroll
    for (int mk = 1; mk < 64; mk <<= 1) { s += __shfl_xor(s, mk); ss += __shfl_xor(ss, mk); }
    __shared__ float red[8];
    int wave = t >> 6, lane = t & 63;
    if (lane == 0) { red[wave * 2] = s; red[wave * 2 + 1] = ss; }
    __syncthreads();
    s = red[0] + red[2] + red[4] + red[6];
    ss = red[1] + red[3] + red[5] + red[7];
    float mu = s * (1.f / 512.f);
    float var = ss * (1.f / 512.f) - mu * mu;
    float inv = rsqrtf(var + 1e-5f);
    float y0 = (v0 - mu) * inv * g[t] + bta[t];
    float y1 = (v1 - mu) * inv * g[t + 256] + bta[t + 256];
    if (out_bf) {
        bf16* orow = out_bf + (size_t)row * 512;
        orow[t] = __float2bfloat16(y0);
        orow[t + 256] = __float2bfloat16(y1);
    } else {
        float* orow = out_f + (size_t)row * 512;
        orow[t] = y0;
        orow[t + 256] = y1;
    }
}

// ---------------------------------------------------------------- launch
extern "C" void kernel_launch(void* const* d_in, const int* in_sizes, int n_in,
                              void* d_out, int out_size, void* d_ws, size_t ws_size,
                              hipStream_t stream) {
    const float* x_enc = (const float*)d_in[0];
    const float* W_emb = (const float*)d_in[1];
    const float* Wq    = (const float*)d_in[2];
    const float* bq    = (const float*)d_in[3];
    const float* Wk    = (const float*)d_in[4];
    const float* bk    = (const float*)d_in[5];
    const float* Wv    = (const float*)d_in[6];
    const float* bv    = (const float*)d_in[7];
    const float* Wo    = (const float*)d_in[8];
    const float* bo    = (const float*)d_in[9];
    const float* ln1_g = (const float*)d_in[10];
    const float* ln1_b = (const float*)d_in[11];
    const float* W1    = (const float*)d_in[12];
    const float* b1    = (const float*)d_in[13];
    const float* W2    = (const float*)d_in[14];
    const float* b2    = (const float*)d_in[15];
    const float* ln2_g = (const float*)d_in[16];
    const float* ln2_b = (const float*)d_in[17];
    const float* lnf_g = (const float*)d_in[18];
    const float* lnf_b = (const float*)d_in[19];

    const int ROWS = 256 * 240;            // 61440
    char* ws = (char*)d_ws;
    const size_t Hb = (size_t)ROWS * 512 * 2;  // 62,914,560 B
    bf16* h    = (bf16*)(ws);
    bf16* qkv  = (bf16*)(ws + Hb);         // [ROWS][1536]; q|k|v
    bf16* oa   = (bf16*)(ws + 4 * Hb);     // attention output [ROWS][512]
    bf16* scr2 = (bf16*)(ws + 5 * Hb);     // vt during attn; oproj; ffnout
    bf16* mid  = qkv;                      // FFN mid [ROWS][2048] aliases qkv+oa (4*Hb)
    bf16* WqkvT = (bf16*)(ws + 6 * Hb);    // [L][1536][512]
    bf16* WoT  = WqkvT + (size_t)3 * 1536 * 512;
    bf16* W1T  = WoT + (size_t)3 * 512 * 512;
    bf16* W2T  = W1T + (size_t)3 * 512 * 2048;
    float* bcat = (float*)(W2T + (size_t)3 * 2048 * 512);   // [L][1536]

    bf16* vt     = scr2;
    bf16* oproj  = scr2;
    bf16* ffnout = scr2;

    dim3 blk(256);
    transpose_f32_bf16<<<dim3(16, 16, 3), blk, 0, stream>>>(Wq, WqkvT, 512, 512, (size_t)1536 * 512);
    transpose_f32_bf16<<<dim3(16, 16, 3), blk, 0, stream>>>(Wk, WqkvT + (size_t)512 * 512, 512, 512, (size_t)1536 * 512);
    transpose_f32_bf16<<<dim3(16, 16, 3), blk, 0, stream>>>(Wv, WqkvT + (size_t)1024 * 512, 512, 512, (size_t)1536 * 512);
    transpose_f32_bf16<<<dim3(16, 16, 3), blk, 0, stream>>>(Wo, WoT, 512, 512, (size_t)512 * 512);
    transpose_f32_bf16<<<dim3(64, 16, 3), blk, 0, stream>>>(W1, W1T, 512, 2048, (size_t)512 * 2048);
    transpose_f32_bf16<<<dim3(16, 64, 3), blk, 0, stream>>>(W2, W2T, 2048, 512, (size_t)2048 * 512);
    concat_bias<<<18, blk, 0, stream>>>(bq, bk, bv, bcat);

    embed_kernel<<<ROWS, blk, 0, stream>>>(x_enc, W_emb, h);

    for (int L = 0; L < 3; ++L) {
        size_t wo = (size_t)L * 512 * 512;
        size_t w1o = (size_t)L * 512 * 2048;
        gemm_direct<512><<<dim3(6, 480), blk, 0, stream>>>(h, WqkvT + (size_t)L * 1536 * 512,
                                                           bcat + L * 1536, qkv, 1536, 0);
        transpose_v<<<dim3(16, 8, 256), blk, 0, stream>>>(qkv, vt);
        attn_mfma<16><<<512, blk, 0, stream>>>(qkv, vt, oa);
        attn_mfma<32><<<1024, blk, 0, stream>>>(qkv, vt, oa);
        attn_mfma<64><<<2048, blk, 0, stream>>>(qkv, vt, oa);
        attn_mfma<128><<<4096, blk, 0, stream>>>(qkv, vt, oa);
        gemm_direct<512><<<dim3(2, 480), blk, 0, stream>>>(oa, WoT + wo, bo + L * 512, oproj, 512, 0);
        ln_kernel<<<ROWS, blk, 0, stream>>>(h, oproj, ln1_g + L * 512, ln1_b + L * 512, h, nullptr);
        gemm_direct<512><<<dim3(8, 480), blk, 0, stream>>>(h, W1T + w1o, b1 + L * 2048, mid, 2048, 1);
        gemm_direct<2048><<<dim3(2, 480), blk, 0, stream>>>(mid, W2T + w1o, b2 + L * 512, ffnout, 512, 0);
        ln_kernel<<<ROWS, blk, 0, stream>>>(h, ffnout, ln2_g + L * 512, ln2_b + L * 512, h, nullptr);
    }
    ln_kernel<<<ROWS, blk, 0, stream>>>(h, nullptr, lnf_g, lnf_b, nullptr, (float*)d_out);
}